// Round 5
// baseline (57.124 us; speedup 1.0000x reference)
//
#include <hip/hip_runtime.h>
#include <math.h>

static constexpr float PI_F = 3.14159265358979323846f;

// dims: N=32768 nodes, NE=3N edges, H=128, PQC=2
// ws layout (floats):
//   [0..96)     seg: 32 x {sum0, sum1, count}
//   [96]        int counter (last-block election)
//   [128..384)  phi table: 64 x {|p0|^2, |p1|^2, Re(p0 p1*), Im(p0 p1*)}
//   [384..416)  U: 4x4 complex row-major [k][c][re,im]
//   [448..3008)  nT: packed node rows 128 x 20 {W1t[0..15], b1, W2a, W2b, pad}
//   [3008..4544) eT: packed edge rows 128 x 12 {W1t[0..7], b1, W2a, pad, pad}
//   [4544..6080) uT: packed upd rows 128 x 12 {W1t[0..5], b1, W2a, W2b, pad..}
//   [6144..6144+2N)  nf (float2 per node)
//   [6144+2N .. +NE) ef1 (edge a only; edge b provably drops out)
#define WS_NT 448
#define WS_ET 3008
#define WS_UT 4544
#define WS_NF 6144

__device__ inline void rot2(float p, float t, float o, float R[2][2][2]) {
    // Rot(p,t,o) = Rz(o) Ry(t) Rz(p)
    float ct = cosf(0.5f*t), st = sinf(0.5f*t);
    float apo = 0.5f*(p+o), amo = 0.5f*(p-o);
    R[0][0][0] =  ct*cosf(apo); R[0][0][1] = -ct*sinf(apo);
    R[0][1][0] = -st*cosf(amo); R[0][1][1] = -st*sinf(amo);
    R[1][0][0] =  st*cosf(amo); R[1][0][1] = -st*sinf(amo);
    R[1][1][0] =  ct*cosf(apo); R[1][1][1] =  ct*sinf(apo);
}

// --- k_prep: zero seg, phi table, U, and transpose+pack all MLP weights ---
__global__ __launch_bounds__(256) void k_prep(
    const float* __restrict__ nW1, const float* __restrict__ nb1, const float* __restrict__ nW2,
    const float* __restrict__ eW1, const float* __restrict__ eb1, const float* __restrict__ eW2,
    const float* __restrict__ uW1, const float* __restrict__ ub1, const float* __restrict__ uW2,
    const float* __restrict__ inits, const float* __restrict__ update,
    float* __restrict__ ws)
{
    const int tid = threadIdx.x;
    if (tid < 96) ws[tid] = 0.f;
    if (tid == 96) ((int*)ws)[96] = 0;

    if (tid < 64) {
        // phi: wire-7 state for control pattern tid
        // bits 0..2 = wires 0,1,2 (CRY ctrl), bits 3..5 = wires 4,5,6 (CRX/CRZ ctrl)
        float cx = cosf(0.5f*inits[0]), sx = sinf(0.5f*inits[0]);
        float cy = cosf(0.5f*inits[1]), sy = sinf(0.5f*inits[1]);
        float cz = cosf(0.5f*inits[2]), sz = sinf(0.5f*inits[2]);
        float v0r = 1.f, v0i = 0.f, v1r = 0.f, v1i = 0.f;
        #pragma unroll
        for (int i = 0; i < 3; ++i) {
            int xb = (tid >> (3+i)) & 1;
            int yb = (tid >> i) & 1;
            if (xb) {
                float n0r = cx*v0r + sx*v1i, n0i = cx*v0i - sx*v1r;
                float n1r = sx*v0i + cx*v1r, n1i = -sx*v0r + cx*v1i;
                v0r=n0r; v0i=n0i; v1r=n1r; v1i=n1i;
            }
            if (yb) {
                float n0r = cy*v0r - sy*v1r, n0i = cy*v0i - sy*v1i;
                float n1r = sy*v0r + cy*v1r, n1i = sy*v0i + cy*v1i;
                v0r=n0r; v0i=n0i; v1r=n1r; v1i=n1i;
            }
            if (xb) {
                float n0r = cz*v0r + sz*v0i, n0i = cz*v0i - sz*v0r;
                float n1r = cz*v1r - sz*v1i, n1i = cz*v1i + sz*v1r;
                v0r=n0r; v0i=n0i; v1r=n1r; v1i=n1i;
            }
        }
        ws[128 + tid*4 + 0] = v0r*v0r + v0i*v0i;
        ws[128 + tid*4 + 1] = v1r*v1r + v1i*v1i;
        ws[128 + tid*4 + 2] = v0r*v1r + v0i*v1i;   // Re(p0 p1*)
        ws[128 + tid*4 + 3] = v0i*v1r - v0r*v1i;   // Im(p0 p1*)
    } else if (tid == 64) {
        // U = CNOT(7,3) CNOT(3,7) (Ra (x) Rb), basis idx = 2*w3 + w7; row perm {0,2,3,1}
        float Ra[2][2][2], Rb[2][2][2];
        rot2(update[0], update[1], update[2], Ra);
        rot2(update[3], update[4], update[5], Rb);
        const int src[4] = {0, 2, 3, 1};
        #pragma unroll
        for (int k = 0; k < 4; ++k) {
            int r = src[k], r3 = r >> 1, r7 = r & 1;
            #pragma unroll
            for (int c = 0; c < 4; ++c) {
                int c3 = c >> 1, c7 = c & 1;
                float ar = Ra[r3][c3][0], ai = Ra[r3][c3][1];
                float br = Rb[r7][c7][0], bi = Rb[r7][c7][1];
                ws[384 + (k*4+c)*2 + 0] = ar*br - ai*bi;
                ws[384 + (k*4+c)*2 + 1] = ar*bi + ai*br;
            }
        }
    }

    if (tid < 128) {
        // node row h = tid
        int h = tid;
        float* r = ws + WS_NT + h*20;
        #pragma unroll
        for (int i = 0; i < 16; ++i) r[i] = nW1[i*128 + h];
        r[16] = nb1[h]; r[17] = nW2[2*h]; r[18] = nW2[2*h+1]; r[19] = 0.f;
    } else {
        // edge + upd rows h = tid-128
        int h = tid - 128;
        float* re = ws + WS_ET + h*12;
        #pragma unroll
        for (int i = 0; i < 8; ++i) re[i] = eW1[i*128 + h];
        re[8] = eb1[h]; re[9] = eW2[2*h]; re[10] = 0.f; re[11] = 0.f;
        float* ru = ws + WS_UT + h*12;
        #pragma unroll
        for (int i = 0; i < 6; ++i) ru[i] = uW1[i*128 + h];
        ru[6] = ub1[h]; ru[7] = uW2[2*h]; ru[8] = uW2[2*h+1];
        ru[9] = 0.f; ru[10] = 0.f; ru[11] = 0.f;
    }
}

// --- k_mlp: edge blocks [0,nbE), node blocks [nbE, nbE+nbN) ; h-streaming, no t-array ---
__global__ __launch_bounds__(256) void k_mlp(
    const float* __restrict__ node_feat, const float* __restrict__ edge_attr,
    const float* __restrict__ nT, const float* __restrict__ eT,
    const float* __restrict__ nb2, const float* __restrict__ eb2,
    float2* __restrict__ nf, float* __restrict__ ef1,
    int N, int NE, int nbE)
{
    const int tid = threadIdx.x;
    const int blk = blockIdx.x;

    if (blk < nbE) {
        int e = blk * 256 + tid;
        if (e >= NE) return;
        const float4* xp = (const float4*)(edge_attr + (size_t)e * 8);
        float4 xv0 = xp[0], xv1 = xp[1];
        float acc = 0.f;
        #pragma unroll 4
        for (int h = 0; h < 128; ++h) {
            const float4* r = (const float4*)(eT + h*12);
            float4 f0 = r[0], f1 = r[1], f2 = r[2];
            float t = f2.x;
            t = fmaf(xv0.x, f0.x, t); t = fmaf(xv0.y, f0.y, t);
            t = fmaf(xv0.z, f0.z, t); t = fmaf(xv0.w, f0.w, t);
            t = fmaf(xv1.x, f1.x, t); t = fmaf(xv1.y, f1.y, t);
            t = fmaf(xv1.z, f1.z, t); t = fmaf(xv1.w, f1.w, t);
            float lt = t > 0.f ? t : 0.01f * t;
            acc = fmaf(lt, f2.y, acc);
        }
        ef1[e] = tanhf(acc + eb2[0]) * PI_F;
    } else {
        int n = (blk - nbE) * 256 + tid;
        if (n >= N) return;
        const float4* xp = (const float4*)(node_feat + (size_t)n * 16);
        float4 xv0 = xp[0], xv1 = xp[1], xv2 = xp[2], xv3 = xp[3];
        float a0 = 0.f, a1 = 0.f;
        #pragma unroll 4
        for (int h = 0; h < 128; ++h) {
            const float4* r = (const float4*)(nT + h*20);
            float4 f0 = r[0], f1 = r[1], f2 = r[2], f3 = r[3], f4 = r[4];
            float t = f4.x;
            t = fmaf(xv0.x, f0.x, t); t = fmaf(xv0.y, f0.y, t);
            t = fmaf(xv0.z, f0.z, t); t = fmaf(xv0.w, f0.w, t);
            t = fmaf(xv1.x, f1.x, t); t = fmaf(xv1.y, f1.y, t);
            t = fmaf(xv1.z, f1.z, t); t = fmaf(xv1.w, f1.w, t);
            t = fmaf(xv2.x, f2.x, t); t = fmaf(xv2.y, f2.y, t);
            t = fmaf(xv2.z, f2.z, t); t = fmaf(xv2.w, f2.w, t);
            t = fmaf(xv3.x, f3.x, t); t = fmaf(xv3.y, f3.y, t);
            t = fmaf(xv3.z, f3.z, t); t = fmaf(xv3.w, f3.w, t);
            float lt = t > 0.f ? t : 0.01f * t;
            a0 = fmaf(lt, f4.y, a0);
            a1 = fmaf(lt, f4.z, a1);
        }
        float2 o;
        o.x = tanhf(a0 + nb2[0]) * PI_F;
        o.y = tanhf(a1 + nb2[1]) * PI_F;
        nf[n] = o;
    }
}

// --- k_circ: analytic circuit + upd MLP + LN + segment reduce + (last block) head ---
__global__ __launch_bounds__(256) void k_circ(
    float* __restrict__ ws,
    const float4* __restrict__ phi4, const float* __restrict__ U,
    const float* __restrict__ uT, const float* __restrict__ ub2,
    const float2* __restrict__ nf, const float* __restrict__ ef1,
    const float* __restrict__ lng, const float* __restrict__ lnb,
    const int* __restrict__ sub_nodes, const int* __restrict__ sub_edges,
    const int* __restrict__ batch,
    const float* __restrict__ hW1, const float* __restrict__ hb1,
    const float* __restrict__ hW2, const float* __restrict__ hb2,
    float* __restrict__ out, int N)
{
    const int tid = threadIdx.x;
    int n0 = blockIdx.x * 256 + tid;
    bool valid = n0 < N;
    int n = valid ? n0 : N - 1;

    const int4 sn = ((const int4*)sub_nodes)[n];
    int se0 = sub_edges[3*(size_t)n+0], se1 = sub_edges[3*(size_t)n+1], se2 = sub_edges[3*(size_t)n+2];

    // control-wire probability weights (cos^2(a/2) = (1+cos a)/2)
    float pe[3][2], pn[3][2];
    {
        float c0 = cosf(ef1[se0]), c1 = cosf(ef1[se1]), c2 = cosf(ef1[se2]);
        pe[0][0]=0.5f*(1.f+c0); pe[0][1]=0.5f*(1.f-c0);
        pe[1][0]=0.5f*(1.f+c1); pe[1][1]=0.5f*(1.f-c1);
        pe[2][0]=0.5f*(1.f+c2); pe[2][1]=0.5f*(1.f-c2);
        float d0 = cosf(nf[sn.y].x), d1 = cosf(nf[sn.z].x), d2 = cosf(nf[sn.w].x);
        pn[0][0]=0.5f*(1.f+d0); pn[0][1]=0.5f*(1.f-d0);
        pn[1][0]=0.5f*(1.f+d1); pn[1][1]=0.5f*(1.f-d1);
        pn[2][0]=0.5f*(1.f+d2); pn[2][1]=0.5f*(1.f-d2);
    }
    float E[8], Nw[8];
    #pragma unroll
    for (int m = 0; m < 8; ++m) {
        E[m]  = pe[0][m&1] * pe[1][(m>>1)&1] * pe[2][(m>>2)&1];
        Nw[m] = pn[0][m&1] * pn[1][(m>>1)&1] * pn[2][(m>>2)&1];
    }
    float S0 = 0.f, S1 = 0.f, Sr = 0.f, Si = 0.f;
    #pragma unroll
    for (int m = 0; m < 64; ++m) {
        float W = E[m & 7] * Nw[m >> 3];
        float4 g = phi4[m];
        S0 = fmaf(W, g.x, S0); S1 = fmaf(W, g.y, S1);
        Sr = fmaf(W, g.z, Sr); Si = fmaf(W, g.w, Si);
    }
    // center qubit + T = U (q3 (x) I) ; P[k]
    float2 nfc = nf[sn.x];
    float ca = cosf(0.5f*nfc.x), sa = sinf(0.5f*nfc.x);
    float cb = cosf(0.5f*nfc.y), sb = sinf(0.5f*nfc.y);
    float q0r = ca*cb, q0i = -ca*sb, q1r = sa*cb, q1i = sa*sb;
    float P[4];
    #pragma unroll
    for (int k = 0; k < 4; ++k) {
        float u0r = U[(k*4+0)*2], u0i = U[(k*4+0)*2+1];
        float u1r = U[(k*4+2)*2], u1i = U[(k*4+2)*2+1];
        float T0r = u0r*q0r - u0i*q0i + u1r*q1r - u1i*q1i;
        float T0i = u0r*q0i + u0i*q0r + u1r*q1i + u1i*q1r;
        float v0r_ = U[(k*4+1)*2], v0i_ = U[(k*4+1)*2+1];
        float v1r_ = U[(k*4+3)*2], v1i_ = U[(k*4+3)*2+1];
        float T1r = v0r_*q0r - v0i_*q0i + v1r_*q1r - v1i_*q1i;
        float T1i = v0r_*q0i + v0i_*q0r + v1r_*q1i + v1i_*q1r;
        float Ar = T0r*T1r + T0i*T1i, Ai = T0i*T1r - T0r*T1i;
        P[k] = (T0r*T0r + T0i*T0i)*S0 + (T1r*T1r + T1i*T1i)*S1 + 2.f*(Ar*Sr - Ai*Si);
    }
    // upd MLP (6->128->2), h-streaming over packed rows
    float u0 = 0.f, u1 = 0.f;
    #pragma unroll 4
    for (int h = 0; h < 128; ++h) {
        const float4* r = (const float4*)(uT + h*12);
        float4 f0 = r[0], f1 = r[1], f2 = r[2];
        float t = f1.z;
        t = fmaf(nfc.x, f0.x, t); t = fmaf(nfc.y, f0.y, t);
        t = fmaf(P[0],  f0.z, t); t = fmaf(P[1],  f0.w, t);
        t = fmaf(P[2],  f1.x, t); t = fmaf(P[3],  f1.y, t);
        float lt = t > 0.f ? t : 0.01f * t;
        u0 = fmaf(lt, f1.w, u0);
        u1 = fmaf(lt, f2.x, u1);
    }
    // x = 1.5*nf + 0.5*upd (centers == arange(N)); LayerNorm over 2 features
    float x0 = 1.5f*nfc.x + 0.5f*(tanhf(u0 + ub2[0]) * PI_F);
    float x1 = 1.5f*nfc.y + 0.5f*(tanhf(u1 + ub2[1]) * PI_F);
    float mu = 0.5f*(x0 + x1);
    float d  = x0 - mu;
    float inv = 1.0f / sqrtf(d*d + 1e-5f);
    float wv  = valid ? 1.f : 0.f;
    float xn0 = ( d*inv*lng[0] + lnb[0]) * wv;
    float xn1 = (-d*inv*lng[1] + lnb[1]) * wv;
    int bs = batch[n];

    // segment accumulate: wave-uniform fast path (batch is sorted), per-lane fallback
    bool uni = __all(bs == __shfl(bs, 0));
    if (uni) {
        float r0 = xn0, r1 = xn1, rc = wv;
        #pragma unroll
        for (int off = 32; off >= 1; off >>= 1) {
            r0 += __shfl_xor(r0, off); r1 += __shfl_xor(r1, off); rc += __shfl_xor(rc, off);
        }
        if ((tid & 63) == 0) {
            atomicAdd(&ws[bs*3+0], r0);
            atomicAdd(&ws[bs*3+1], r1);
            atomicAdd(&ws[bs*3+2], rc);
        }
    } else if (valid) {
        atomicAdd(&ws[bs*3+0], xn0);
        atomicAdd(&ws[bs*3+1], xn1);
        atomicAdd(&ws[bs*3+2], 1.f);
    }

    // last-block election -> head MLP (2->2 leaky 2->2) on segment means
    __shared__ int sLast;
    __threadfence();
    __syncthreads();
    if (tid == 0) {
        int old = atomicAdd((int*)ws + 96, 1);
        sLast = (old == (int)gridDim.x - 1) ? 1 : 0;
    }
    __syncthreads();
    if (sLast && tid < 32) {
        float cnt = atomicAdd(&ws[tid*3+2], 0.f);
        float iv  = cnt > 0.f ? 1.f/cnt : 0.f;
        float g0  = atomicAdd(&ws[tid*3+0], 0.f) * iv;
        float g1  = atomicAdd(&ws[tid*3+1], 0.f) * iv;
        float a = hb1[0] + g0*hW1[0] + g1*hW1[2];
        float b = hb1[1] + g0*hW1[1] + g1*hW1[3];
        float h0 = a > 0.f ? a : 0.01f*a;
        float h1 = b > 0.f ? b : 0.01f*b;
        out[tid*2+0] = hb2[0] + h0*hW2[0] + h1*hW2[2];
        out[tid*2+1] = hb2[1] + h0*hW2[1] + h1*hW2[3];
    }
}

extern "C" void kernel_launch(void* const* d_in, const int* in_sizes, int n_in,
                              void* d_out, int out_size, void* d_ws, size_t ws_size,
                              hipStream_t stream)
{
    const float* node_feat = (const float*)d_in[0];
    const float* edge_attr = (const float*)d_in[1];
    const float* node_W1 = (const float*)d_in[2];
    const float* node_b1 = (const float*)d_in[3];
    const float* node_W2 = (const float*)d_in[4];
    const float* node_b2 = (const float*)d_in[5];
    const float* edge_W1 = (const float*)d_in[6];
    const float* edge_b1 = (const float*)d_in[7];
    const float* edge_W2 = (const float*)d_in[8];
    const float* edge_b2 = (const float*)d_in[9];
    const float* inits   = (const float*)d_in[10];
    const float* update  = (const float*)d_in[11];
    const float* upd_W1  = (const float*)d_in[12];
    const float* upd_b1  = (const float*)d_in[13];
    const float* upd_W2  = (const float*)d_in[14];
    const float* upd_b2  = (const float*)d_in[15];
    const float* ln_g    = (const float*)d_in[16];
    const float* ln_b    = (const float*)d_in[17];
    const float* head_W1 = (const float*)d_in[18];
    const float* head_b1 = (const float*)d_in[19];
    const float* head_W2 = (const float*)d_in[20];
    const float* head_b2 = (const float*)d_in[21];
    const int* sub_nodes = (const int*)d_in[22];
    const int* sub_edges = (const int*)d_in[23];
    const int* batch     = (const int*)d_in[24];

    int N  = in_sizes[24];      // 32768
    int NE = in_sizes[1] / 8;   // 98304

    float* w = (float*)d_ws;
    size_t need = ((size_t)WS_NF + 2*(size_t)N + (size_t)NE) * sizeof(float);
    if (ws_size < need) return;

    float2* nf = (float2*)(w + WS_NF);
    float* ef1 = w + WS_NF + 2*(size_t)N;

    int nbE = (NE + 255) / 256;
    int nbN = (N + 255) / 256;

    k_prep<<<1, 256, 0, stream>>>(node_W1, node_b1, node_W2,
                                  edge_W1, edge_b1, edge_W2,
                                  upd_W1, upd_b1, upd_W2,
                                  inits, update, w);
    k_mlp<<<nbE + nbN, 256, 0, stream>>>(node_feat, edge_attr,
        w + WS_NT, w + WS_ET, node_b2, edge_b2, nf, ef1, N, NE, nbE);
    k_circ<<<nbN, 256, 0, stream>>>(w,
        (const float4*)(w + 128), w + 384, w + WS_UT, upd_b2,
        nf, ef1, ln_g, ln_b, sub_nodes, sub_edges, batch,
        head_W1, head_b1, head_W2, head_b2,
        (float*)d_out, N);
}

// Round 6
// 46.914 us; speedup vs baseline: 1.2176x; 1.2176x over previous
//
#include <hip/hip_runtime.h>
#include <math.h>

static constexpr float PI_F = 3.14159265358979323846f;

// ws layout (floats):
//   [0..96)   seg: 32 x {sum0, sum1, count}
//   [96]      int counter (last-block election)
//   [128..128+2N)       nf (float2 per node)
//   [128+2N..128+2N+NE) ef1 (edge a-angle only; edge b provably drops out)
#define WS_NF 128

__device__ inline void rot2(float p, float t, float o, float R[2][2][2]) {
    // Rot(p,t,o) = Rz(o) Ry(t) Rz(p)
    float ct = cosf(0.5f*t), st = sinf(0.5f*t);
    float apo = 0.5f*(p+o), amo = 0.5f*(p-o);
    R[0][0][0] =  ct*cosf(apo); R[0][0][1] = -ct*sinf(apo);
    R[0][1][0] = -st*cosf(amo); R[0][1][1] = -st*sinf(amo);
    R[1][0][0] =  st*cosf(amo); R[1][0][1] = -st*sinf(amo);
    R[1][1][0] =  ct*cosf(apo); R[1][1][1] =  ct*sinf(apo);
}

// --- k_mlp: 128-thread blocks, M=2 items/thread.
// blocks [0, nbE): edge MLP (8->128->1, col 0 only). blocks [nbE, nbE+nbN): node MLP (16->128->2).
// Weights staged once per block into LDS in transposed packed rows -> ds_read_b128 broadcast.
__global__ __launch_bounds__(128) void k_mlp(
    const float* __restrict__ node_feat, const float* __restrict__ edge_attr,
    const float* __restrict__ nW1, const float* __restrict__ nb1,
    const float* __restrict__ nW2, const float* __restrict__ nb2,
    const float* __restrict__ eW1, const float* __restrict__ eb1,
    const float* __restrict__ eW2, const float* __restrict__ eb2,
    float* __restrict__ ws, float2* __restrict__ nf, float* __restrict__ ef1,
    int N, int NE, int nbE)
{
    __shared__ __align__(16) float sW[128*20];
    const int tid = threadIdx.x;
    const int blk = blockIdx.x;

    if (blk == 0) {   // zero seg accumulators + counter (runs strictly before k_circ)
        if (tid < 96) ws[tid] = 0.f;
        if (tid == 96) ((int*)ws)[96] = 0;
    }

    if (blk < nbE) {
        // ---- edge path: rows of 12 floats {W1t[0..7], b1, W2a, pad, pad} ----
        for (int idx = tid; idx < 1024; idx += 128)
            sW[(idx & 127)*12 + (idx >> 7)] = eW1[idx];        // coalesced read, LDS transpose
        if (tid < 128) { sW[tid*12+8] = eb1[tid]; sW[tid*12+9] = eW2[2*tid]; }
        __syncthreads();

        int e0 = blk*256 + tid, e1 = e0 + 128;
        bool v0 = e0 < NE, v1 = e1 < NE;
        int e0c = v0 ? e0 : 0, e1c = v1 ? e1 : 0;
        const float4* p0 = (const float4*)(edge_attr + (size_t)e0c * 8);
        const float4* p1 = (const float4*)(edge_attr + (size_t)e1c * 8);
        float4 a0 = p0[0], a1 = p0[1], b0 = p1[0], b1v = p1[1];
        float acc0 = 0.f, acc1 = 0.f;
        #pragma unroll 4
        for (int h = 0; h < 128; ++h) {
            const float4* r = (const float4*)&sW[h*12];
            float4 f0 = r[0], f1 = r[1], f2 = r[2];
            float t0 = f2.x, t1 = f2.x;
            t0 = fmaf(a0.x, f0.x, t0); t1 = fmaf(b0.x, f0.x, t1);
            t0 = fmaf(a0.y, f0.y, t0); t1 = fmaf(b0.y, f0.y, t1);
            t0 = fmaf(a0.z, f0.z, t0); t1 = fmaf(b0.z, f0.z, t1);
            t0 = fmaf(a0.w, f0.w, t0); t1 = fmaf(b0.w, f0.w, t1);
            t0 = fmaf(a1.x, f1.x, t0); t1 = fmaf(b1v.x, f1.x, t1);
            t0 = fmaf(a1.y, f1.y, t0); t1 = fmaf(b1v.y, f1.y, t1);
            t0 = fmaf(a1.z, f1.z, t0); t1 = fmaf(b1v.z, f1.z, t1);
            t0 = fmaf(a1.w, f1.w, t0); t1 = fmaf(b1v.w, f1.w, t1);
            float l0 = t0 > 0.f ? t0 : 0.01f*t0;
            float l1 = t1 > 0.f ? t1 : 0.01f*t1;
            acc0 = fmaf(l0, f2.y, acc0);
            acc1 = fmaf(l1, f2.y, acc1);
        }
        float bb = eb2[0];
        if (v0) ef1[e0] = tanhf(acc0 + bb) * PI_F;
        if (v1) ef1[e1] = tanhf(acc1 + bb) * PI_F;
    } else {
        // ---- node path: rows of 20 floats {W1t[0..15], b1, W2a, W2b, pad} ----
        for (int idx = tid; idx < 2048; idx += 128)
            sW[(idx & 127)*20 + (idx >> 7)] = nW1[idx];
        if (tid < 128) {
            sW[tid*20+16] = nb1[tid];
            sW[tid*20+17] = nW2[2*tid];
            sW[tid*20+18] = nW2[2*tid+1];
        }
        __syncthreads();

        int n0 = (blk - nbE)*256 + tid, n1 = n0 + 128;
        bool v0 = n0 < N, v1 = n1 < N;
        int n0c = v0 ? n0 : 0, n1c = v1 ? n1 : 0;
        const float4* p0 = (const float4*)(node_feat + (size_t)n0c * 16);
        const float4* p1 = (const float4*)(node_feat + (size_t)n1c * 16);
        float4 a0 = p0[0], a1 = p0[1], a2 = p0[2], a3 = p0[3];
        float4 b0 = p1[0], b1v = p1[1], b2v = p1[2], b3v = p1[3];
        float x00 = 0.f, x01 = 0.f, y00 = 0.f, y01 = 0.f;
        #pragma unroll 4
        for (int h = 0; h < 128; ++h) {
            const float4* r = (const float4*)&sW[h*20];
            float4 f0 = r[0], f1 = r[1], f2 = r[2], f3 = r[3], f4 = r[4];
            float t0 = f4.x, t1 = f4.x;
            t0 = fmaf(a0.x, f0.x, t0); t1 = fmaf(b0.x, f0.x, t1);
            t0 = fmaf(a0.y, f0.y, t0); t1 = fmaf(b0.y, f0.y, t1);
            t0 = fmaf(a0.z, f0.z, t0); t1 = fmaf(b0.z, f0.z, t1);
            t0 = fmaf(a0.w, f0.w, t0); t1 = fmaf(b0.w, f0.w, t1);
            t0 = fmaf(a1.x, f1.x, t0); t1 = fmaf(b1v.x, f1.x, t1);
            t0 = fmaf(a1.y, f1.y, t0); t1 = fmaf(b1v.y, f1.y, t1);
            t0 = fmaf(a1.z, f1.z, t0); t1 = fmaf(b1v.z, f1.z, t1);
            t0 = fmaf(a1.w, f1.w, t0); t1 = fmaf(b1v.w, f1.w, t1);
            t0 = fmaf(a2.x, f2.x, t0); t1 = fmaf(b2v.x, f2.x, t1);
            t0 = fmaf(a2.y, f2.y, t0); t1 = fmaf(b2v.y, f2.y, t1);
            t0 = fmaf(a2.z, f2.z, t0); t1 = fmaf(b2v.z, f2.z, t1);
            t0 = fmaf(a2.w, f2.w, t0); t1 = fmaf(b2v.w, f2.w, t1);
            t0 = fmaf(a3.x, f3.x, t0); t1 = fmaf(b3v.x, f3.x, t1);
            t0 = fmaf(a3.y, f3.y, t0); t1 = fmaf(b3v.y, f3.y, t1);
            t0 = fmaf(a3.z, f3.z, t0); t1 = fmaf(b3v.z, f3.z, t1);
            t0 = fmaf(a3.w, f3.w, t0); t1 = fmaf(b3v.w, f3.w, t1);
            float l0 = t0 > 0.f ? t0 : 0.01f*t0;
            float l1 = t1 > 0.f ? t1 : 0.01f*t1;
            x00 = fmaf(l0, f4.y, x00); x01 = fmaf(l0, f4.z, x01);
            y00 = fmaf(l1, f4.y, y00); y01 = fmaf(l1, f4.z, y01);
        }
        float c0 = nb2[0], c1 = nb2[1];
        if (v0) { float2 o; o.x = tanhf(x00+c0)*PI_F; o.y = tanhf(x01+c1)*PI_F; nf[n0] = o; }
        if (v1) { float2 o; o.x = tanhf(y00+c0)*PI_F; o.y = tanhf(y01+c1)*PI_F; nf[n1] = o; }
    }
}

// --- k_circ: 128-thread blocks, 1 node/thread.
// In-block: recompute phi table + U, stage upd rows. Then analytic circuit + upd MLP +
// LN + segment reduce + last-block head.
__global__ __launch_bounds__(128) void k_circ(
    float* __restrict__ ws, const float2* __restrict__ nf, const float* __restrict__ ef1,
    const float* __restrict__ uW1, const float* __restrict__ ub1,
    const float* __restrict__ uW2, const float* __restrict__ ub2,
    const float* __restrict__ inits, const float* __restrict__ update,
    const float* __restrict__ lng, const float* __restrict__ lnb,
    const int* __restrict__ sub_nodes, const int* __restrict__ sub_edges,
    const int* __restrict__ batch,
    const float* __restrict__ hW1, const float* __restrict__ hb1,
    const float* __restrict__ hW2, const float* __restrict__ hb2,
    float* __restrict__ out, int N)
{
    __shared__ __align__(16) float sU[128*12];   // upd rows {W1t[0..5], b1, W2a, W2b, pad x3}
    __shared__ float4 sPhi[64];
    __shared__ float sUm[32];
    const int tid = threadIdx.x;

    for (int idx = tid; idx < 768; idx += 128)
        sU[(idx & 127)*12 + (idx >> 7)] = uW1[idx];
    if (tid < 128) {
        sU[tid*12+6] = ub1[tid];
        sU[tid*12+7] = uW2[2*tid];
        sU[tid*12+8] = uW2[2*tid+1];
    }
    if (tid < 64) {
        // phi: wire-7 state for control pattern tid
        // bits 0..2 = wires 0,1,2 (CRY ctrl), bits 3..5 = wires 4,5,6 (CRX/CRZ ctrl)
        float cx = cosf(0.5f*inits[0]), sx = sinf(0.5f*inits[0]);
        float cy = cosf(0.5f*inits[1]), sy = sinf(0.5f*inits[1]);
        float cz = cosf(0.5f*inits[2]), sz = sinf(0.5f*inits[2]);
        float v0r = 1.f, v0i = 0.f, v1r = 0.f, v1i = 0.f;
        #pragma unroll
        for (int i = 0; i < 3; ++i) {
            int xb = (tid >> (3+i)) & 1;
            int yb = (tid >> i) & 1;
            if (xb) {
                float n0r = cx*v0r + sx*v1i, n0i = cx*v0i - sx*v1r;
                float n1r = sx*v0i + cx*v1r, n1i = -sx*v0r + cx*v1i;
                v0r=n0r; v0i=n0i; v1r=n1r; v1i=n1i;
            }
            if (yb) {
                float n0r = cy*v0r - sy*v1r, n0i = cy*v0i - sy*v1i;
                float n1r = sy*v0r + cy*v1r, n1i = sy*v0i + cy*v1i;
                v0r=n0r; v0i=n0i; v1r=n1r; v1i=n1i;
            }
            if (xb) {
                float n0r = cz*v0r + sz*v0i, n0i = cz*v0i - sz*v0r;
                float n1r = cz*v1r - sz*v1i, n1i = cz*v1i + sz*v1r;
                v0r=n0r; v0i=n0i; v1r=n1r; v1i=n1i;
            }
        }
        float4 g;
        g.x = v0r*v0r + v0i*v0i;
        g.y = v1r*v1r + v1i*v1i;
        g.z = v0r*v1r + v0i*v1i;   // Re(p0 p1*)
        g.w = v0i*v1r - v0r*v1i;   // Im(p0 p1*)
        sPhi[tid] = g;
    } else if (tid == 64) {
        // U = CNOT(7,3) CNOT(3,7) (Ra (x) Rb), basis idx = 2*w3 + w7; row perm {0,2,3,1}
        float Ra[2][2][2], Rb[2][2][2];
        rot2(update[0], update[1], update[2], Ra);
        rot2(update[3], update[4], update[5], Rb);
        const int src[4] = {0, 2, 3, 1};
        #pragma unroll
        for (int k = 0; k < 4; ++k) {
            int r = src[k], r3 = r >> 1, r7 = r & 1;
            #pragma unroll
            for (int c = 0; c < 4; ++c) {
                int c3 = c >> 1, c7 = c & 1;
                float ar = Ra[r3][c3][0], ai = Ra[r3][c3][1];
                float br = Rb[r7][c7][0], bi = Rb[r7][c7][1];
                sUm[(k*4+c)*2 + 0] = ar*br - ai*bi;
                sUm[(k*4+c)*2 + 1] = ar*bi + ai*br;
            }
        }
    }
    __syncthreads();

    int n0 = blockIdx.x * 128 + tid;
    bool valid = n0 < N;
    int n = valid ? n0 : N - 1;

    const int4 sn = ((const int4*)sub_nodes)[n];
    int se0 = sub_edges[3*(size_t)n+0], se1 = sub_edges[3*(size_t)n+1], se2 = sub_edges[3*(size_t)n+2];

    // control-wire probability weights (cos^2(a/2) = (1+cos a)/2)
    float pe[3][2], pn[3][2];
    {
        float c0 = cosf(ef1[se0]), c1 = cosf(ef1[se1]), c2 = cosf(ef1[se2]);
        pe[0][0]=0.5f*(1.f+c0); pe[0][1]=0.5f*(1.f-c0);
        pe[1][0]=0.5f*(1.f+c1); pe[1][1]=0.5f*(1.f-c1);
        pe[2][0]=0.5f*(1.f+c2); pe[2][1]=0.5f*(1.f-c2);
        float d0 = cosf(nf[sn.y].x), d1 = cosf(nf[sn.z].x), d2 = cosf(nf[sn.w].x);
        pn[0][0]=0.5f*(1.f+d0); pn[0][1]=0.5f*(1.f-d0);
        pn[1][0]=0.5f*(1.f+d1); pn[1][1]=0.5f*(1.f-d1);
        pn[2][0]=0.5f*(1.f+d2); pn[2][1]=0.5f*(1.f-d2);
    }
    float E[8], Nw[8];
    #pragma unroll
    for (int m = 0; m < 8; ++m) {
        E[m]  = pe[0][m&1] * pe[1][(m>>1)&1] * pe[2][(m>>2)&1];
        Nw[m] = pn[0][m&1] * pn[1][(m>>1)&1] * pn[2][(m>>2)&1];
    }
    float S0 = 0.f, S1 = 0.f, Sr = 0.f, Si = 0.f;
    #pragma unroll
    for (int m = 0; m < 64; ++m) {
        float W = E[m & 7] * Nw[m >> 3];
        float4 g = sPhi[m];
        S0 = fmaf(W, g.x, S0); S1 = fmaf(W, g.y, S1);
        Sr = fmaf(W, g.z, Sr); Si = fmaf(W, g.w, Si);
    }
    // center qubit + T = U (q3 (x) I) ; P[k]
    float2 nfc = nf[sn.x];
    float ca = cosf(0.5f*nfc.x), sa = sinf(0.5f*nfc.x);
    float cb = cosf(0.5f*nfc.y), sb = sinf(0.5f*nfc.y);
    float q0r = ca*cb, q0i = -ca*sb, q1r = sa*cb, q1i = sa*sb;
    float P[4];
    #pragma unroll
    for (int k = 0; k < 4; ++k) {
        float u0r = sUm[(k*4+0)*2], u0i = sUm[(k*4+0)*2+1];
        float u1r = sUm[(k*4+2)*2], u1i = sUm[(k*4+2)*2+1];
        float T0r = u0r*q0r - u0i*q0i + u1r*q1r - u1i*q1i;
        float T0i = u0r*q0i + u0i*q0r + u1r*q1i + u1i*q1r;
        float w0r = sUm[(k*4+1)*2], w0i = sUm[(k*4+1)*2+1];
        float w1r = sUm[(k*4+3)*2], w1i = sUm[(k*4+3)*2+1];
        float T1r = w0r*q0r - w0i*q0i + w1r*q1r - w1i*q1i;
        float T1i = w0r*q0i + w0i*q0r + w1r*q1i + w1i*q1r;
        float Ar = T0r*T1r + T0i*T1i, Ai = T0i*T1r - T0r*T1i;
        P[k] = (T0r*T0r + T0i*T0i)*S0 + (T1r*T1r + T1i*T1i)*S1 + 2.f*(Ar*Sr - Ai*Si);
    }
    // upd MLP (6->128->2) over packed LDS rows
    float u0 = 0.f, u1 = 0.f;
    #pragma unroll 4
    for (int h = 0; h < 128; ++h) {
        const float4* r = (const float4*)&sU[h*12];
        float4 f0 = r[0], f1 = r[1], f2 = r[2];
        float t = f1.z;
        t = fmaf(nfc.x, f0.x, t); t = fmaf(nfc.y, f0.y, t);
        t = fmaf(P[0],  f0.z, t); t = fmaf(P[1],  f0.w, t);
        t = fmaf(P[2],  f1.x, t); t = fmaf(P[3],  f1.y, t);
        float lt = t > 0.f ? t : 0.01f * t;
        u0 = fmaf(lt, f1.w, u0);
        u1 = fmaf(lt, f2.x, u1);
    }
    // x = 1.5*nf + 0.5*upd (centers == arange(N)); LayerNorm over 2 features
    float x0 = 1.5f*nfc.x + 0.5f*(tanhf(u0 + ub2[0]) * PI_F);
    float x1 = 1.5f*nfc.y + 0.5f*(tanhf(u1 + ub2[1]) * PI_F);
    float mu = 0.5f*(x0 + x1);
    float d  = x0 - mu;
    float inv = 1.0f / sqrtf(d*d + 1e-5f);
    float wv  = valid ? 1.f : 0.f;
    float xn0 = ( d*inv*lng[0] + lnb[0]) * wv;
    float xn1 = (-d*inv*lng[1] + lnb[1]) * wv;
    int bs = batch[n];

    // segment accumulate: wave-uniform fast path (64 | 1024 so always uniform), fallback kept
    bool uni = __all(bs == __shfl(bs, 0));
    if (uni) {
        float r0 = xn0, r1 = xn1, rc = wv;
        #pragma unroll
        for (int off = 32; off >= 1; off >>= 1) {
            r0 += __shfl_xor(r0, off); r1 += __shfl_xor(r1, off); rc += __shfl_xor(rc, off);
        }
        if ((tid & 63) == 0) {
            atomicAdd(&ws[bs*3+0], r0);
            atomicAdd(&ws[bs*3+1], r1);
            atomicAdd(&ws[bs*3+2], rc);
        }
    } else if (valid) {
        atomicAdd(&ws[bs*3+0], xn0);
        atomicAdd(&ws[bs*3+1], xn1);
        atomicAdd(&ws[bs*3+2], 1.f);
    }

    // last-block election -> head MLP (2->2 leaky 2->2) on segment means
    __shared__ int sLast;
    __threadfence();
    __syncthreads();
    if (tid == 0) {
        int old = atomicAdd((int*)ws + 96, 1);
        sLast = (old == (int)gridDim.x - 1) ? 1 : 0;
    }
    __syncthreads();
    if (sLast && tid < 32) {
        float cnt = atomicAdd(&ws[tid*3+2], 0.f);
        float iv  = cnt > 0.f ? 1.f/cnt : 0.f;
        float g0  = atomicAdd(&ws[tid*3+0], 0.f) * iv;
        float g1  = atomicAdd(&ws[tid*3+1], 0.f) * iv;
        float a = hb1[0] + g0*hW1[0] + g1*hW1[2];
        float b = hb1[1] + g0*hW1[1] + g1*hW1[3];
        float h0 = a > 0.f ? a : 0.01f*a;
        float h1 = b > 0.f ? b : 0.01f*b;
        out[tid*2+0] = hb2[0] + h0*hW2[0] + h1*hW2[2];
        out[tid*2+1] = hb2[1] + h0*hW2[1] + h1*hW2[3];
    }
}

extern "C" void kernel_launch(void* const* d_in, const int* in_sizes, int n_in,
                              void* d_out, int out_size, void* d_ws, size_t ws_size,
                              hipStream_t stream)
{
    const float* node_feat = (const float*)d_in[0];
    const float* edge_attr = (const float*)d_in[1];
    const float* node_W1 = (const float*)d_in[2];
    const float* node_b1 = (const float*)d_in[3];
    const float* node_W2 = (const float*)d_in[4];
    const float* node_b2 = (const float*)d_in[5];
    const float* edge_W1 = (const float*)d_in[6];
    const float* edge_b1 = (const float*)d_in[7];
    const float* edge_W2 = (const float*)d_in[8];
    const float* edge_b2 = (const float*)d_in[9];
    const float* inits   = (const float*)d_in[10];
    const float* update  = (const float*)d_in[11];
    const float* upd_W1  = (const float*)d_in[12];
    const float* upd_b1  = (const float*)d_in[13];
    const float* upd_W2  = (const float*)d_in[14];
    const float* upd_b2  = (const float*)d_in[15];
    const float* ln_g    = (const float*)d_in[16];
    const float* ln_b    = (const float*)d_in[17];
    const float* head_W1 = (const float*)d_in[18];
    const float* head_b1 = (const float*)d_in[19];
    const float* head_W2 = (const float*)d_in[20];
    const float* head_b2 = (const float*)d_in[21];
    const int* sub_nodes = (const int*)d_in[22];
    const int* sub_edges = (const int*)d_in[23];
    const int* batch     = (const int*)d_in[24];

    int N  = in_sizes[24];      // 32768
    int NE = in_sizes[1] / 8;   // 98304

    float* w = (float*)d_ws;
    size_t need = ((size_t)WS_NF + 2*(size_t)N + (size_t)NE) * sizeof(float);
    if (ws_size < need) return;

    float2* nf = (float2*)(w + WS_NF);
    float* ef1 = w + WS_NF + 2*(size_t)N;

    int nbE = (NE + 255) / 256;   // 384 blocks, 2 edges/thread
    int nbN = (N + 255) / 256;    // 128 blocks, 2 nodes/thread
    int nbC = (N + 127) / 128;    // 256 blocks, 1 node/thread

    k_mlp<<<nbE + nbN, 128, 0, stream>>>(node_feat, edge_attr,
        node_W1, node_b1, node_W2, node_b2,
        edge_W1, edge_b1, edge_W2, edge_b2,
        w, nf, ef1, N, NE, nbE);
    k_circ<<<nbC, 128, 0, stream>>>(w, nf, ef1,
        upd_W1, upd_b1, upd_W2, upd_b2,
        inits, update, ln_g, ln_b,
        sub_nodes, sub_edges, batch,
        head_W1, head_b1, head_W2, head_b2,
        (float*)d_out, N);
}